// Round 1
// baseline (135.804 us; speedup 1.0000x reference)
//
#include <hip/hip_runtime.h>

// Problem constants (B,S,H,D fixed by the reference)
#define BB   2
#define SS   2048
#define HH   16
#define DD   64
#define CC   128              // chunk length
#define NCH  (SS/CC)          // 16 chunks per (b,h)
#define RECF (DD*DD + DD)     // 4160 floats per (b,h,chunk) record: KV sum + ksum
#define BHN  (BB*HH)          // 32

__device__ __forceinline__ float elu1(float x) {
    // elu(x)+1 = x+1 (x>0) else exp(x)
    return x > 0.0f ? x + 1.0f : __expf(x);
}

// ---------------------------------------------------------------------------
// Kernel 1: per-chunk KV outer-product sums and k sums.
// grid = BHN*NCH blocks, 256 threads. Thread (d = tid>>2, sub = tid&3) owns
// state row d, cols [sub*16, sub*16+16).
// ---------------------------------------------------------------------------
__global__ __launch_bounds__(256) void k_chunksum(const float* __restrict__ qk,
                                                  const float* __restrict__ v,
                                                  float* __restrict__ ws) {
    const int blk = blockIdx.x;
    const int c   = blk % NCH;
    const int bh  = blk / NCH;
    const int b = bh / HH, h = bh % HH;
    const int tid = threadIdx.x;
    const int d   = tid >> 2;
    const int sub = tid & 3;

    __shared__ float kt[32][DD];
    __shared__ float vt[32][DD];

    float st[16];
#pragma unroll
    for (int e = 0; e < 16; ++e) st[e] = 0.0f;
    float ks = 0.0f;

#pragma unroll 1
    for (int t = 0; t < CC/32; ++t) {
        const int s0 = c*CC + t*32;
#pragma unroll
        for (int l = 0; l < 2; ++l) {
            const int idx  = tid + l*256;      // float4 index, 0..511
            const int row  = idx >> 4;         // 0..31
            const int col4 = (idx & 15) * 4;
            const int s = s0 + row;
            float4 kq = *(const float4*)(qk + ((((size_t)b*SS + s)*2 + 1)*HH + h)*DD + col4);
            kq.x = elu1(kq.x); kq.y = elu1(kq.y); kq.z = elu1(kq.z); kq.w = elu1(kq.w);
            *(float4*)(&kt[row][col4]) = kq;
            *(float4*)(&vt[row][col4]) =
                *(const float4*)(v + (((size_t)b*SS + s)*HH + h)*DD + col4);
        }
        __syncthreads();
#pragma unroll 4
        for (int s = 0; s < 32; ++s) {
            const float kd = kt[s][d];
            ks += kd;
#pragma unroll
            for (int e = 0; e < 16; ++e)
                st[e] = fmaf(kd, vt[s][sub*16 + e], st[e]);
        }
        __syncthreads();
    }

    float* rec = ws + (size_t)(bh*NCH + c) * RECF;
#pragma unroll
    for (int e4 = 0; e4 < 4; ++e4) {
        float4 o = make_float4(st[e4*4], st[e4*4+1], st[e4*4+2], st[e4*4+3]);
        *(float4*)(rec + d*DD + sub*16 + e4*4) = o;
    }
    if (sub == 0) rec[DD*DD + d] = ks;
}

// ---------------------------------------------------------------------------
// Kernel 2: in-place exclusive prefix scan over chunks, parallel over the
// 4160 state elements per (b,h). Coalesced: consecutive threads touch
// consecutive addresses at each chunk step.
// ---------------------------------------------------------------------------
__global__ __launch_bounds__(256) void k_scan(float* __restrict__ ws) {
    const int bh   = blockIdx.x / 17;
    const int elem = (blockIdx.x % 17) * 256 + threadIdx.x;
    if (elem >= RECF) return;
    float pref = 0.0f;
#pragma unroll 1
    for (int c = 0; c < NCH; ++c) {
        float* p = ws + (size_t)(bh*NCH + c)*RECF + elem;
        const float val = *p;
        *p = pref;          // exclusive prefix (state BEFORE this chunk)
        pref += val;
    }
}

// ---------------------------------------------------------------------------
// Kernel 3: outputs. grid = BHN*NCH blocks, 512 threads.
// Thread (i = tid>>2, sub = tid&3) computes row i, output cols [sub*16,+16).
// out_i = q_i @ State_prefix + sum_{j<=i} (q_i.k_j) v_j, normalized by
// q_i.ksum_prefix + cumsum(q_i.k_j). QK dots quad-reduced via shfl_xor.
// ---------------------------------------------------------------------------
__global__ __launch_bounds__(512) void k_out(const float* __restrict__ qk,
                                             const float* __restrict__ v,
                                             const float* __restrict__ ws,
                                             float* __restrict__ out) {
    const int blk = blockIdx.x;
    const int c   = blk % NCH;
    const int bh  = blk / NCH;
    const int b = bh / HH, h = bh % HH;
    const int tid  = threadIdx.x;
    const int i    = tid >> 2;
    const int sub  = tid & 3;
    const int cols = sub * 16;

    __shared__ float Kl[CC][DD];   // 32 KB
    __shared__ float Vl[CC][DD];   // 32 KB

    // Stage K (with elu+1) and V for this chunk into LDS. Coalesced float4.
#pragma unroll
    for (int l = 0; l < 4; ++l) {
        const int idx  = tid + l*512;      // float4 index, 0..2047
        const int row  = idx >> 4;
        const int col4 = (idx & 15) * 4;
        const int s = c*CC + row;
        float4 kq = *(const float4*)(qk + ((((size_t)b*SS + s)*2 + 1)*HH + h)*DD + col4);
        kq.x = elu1(kq.x); kq.y = elu1(kq.y); kq.z = elu1(kq.z); kq.w = elu1(kq.w);
        *(float4*)(&Kl[row][col4]) = kq;
        *(float4*)(&Vl[row][col4]) =
            *(const float4*)(v + (((size_t)b*SS + s)*HH + h)*DD + col4);
    }

    const int s = c*CC + i;
    const float* qp  = qk + ((((size_t)b*SS + s)*2 + 0)*HH + h)*DD;
    const float* rec = ws + (size_t)(bh*NCH + c) * RECF;

    // q slice for dot-product partials (own 16 dims), statically indexed
    float qpart[16];
#pragma unroll
    for (int e4 = 0; e4 < 4; ++e4) {
        float4 t = *(const float4*)(qp + cols + e4*4);
        qpart[e4*4+0] = elu1(t.x); qpart[e4*4+1] = elu1(t.y);
        qpart[e4*4+2] = elu1(t.z); qpart[e4*4+3] = elu1(t.w);
    }

    float acc[16];
#pragma unroll
    for (int e = 0; e < 16; ++e) acc[e] = 0.0f;

    // Inter-chunk: acc[e] += q[d] * State[d][cols+e]  (State L1-cached, 16 KB/block)
#pragma unroll
    for (int d4 = 0; d4 < 16; ++d4) {
        float4 qv = *(const float4*)(qp + d4*4);
        qv.x = elu1(qv.x); qv.y = elu1(qv.y); qv.z = elu1(qv.z); qv.w = elu1(qv.w);
        const float qd[4] = {qv.x, qv.y, qv.z, qv.w};
#pragma unroll
        for (int dd = 0; dd < 4; ++dd) {
            const float* srow = rec + (d4*4 + dd)*DD + cols;
#pragma unroll
            for (int e4 = 0; e4 < 4; ++e4) {
                float4 t = *(const float4*)(srow + e4*4);
                acc[e4*4+0] = fmaf(qd[dd], t.x, acc[e4*4+0]);
                acc[e4*4+1] = fmaf(qd[dd], t.y, acc[e4*4+1]);
                acc[e4*4+2] = fmaf(qd[dd], t.z, acc[e4*4+2]);
                acc[e4*4+3] = fmaf(qd[dd], t.w, acc[e4*4+3]);
            }
        }
    }

    // Denominator, inter part: q . ksum_prefix (quad-reduced)
    float pd = 0.0f;
#pragma unroll
    for (int e4 = 0; e4 < 4; ++e4) {
        float4 t = *(const float4*)(rec + DD*DD + cols + e4*4);
        pd = fmaf(qpart[e4*4+0], t.x, pd);
        pd = fmaf(qpart[e4*4+1], t.y, pd);
        pd = fmaf(qpart[e4*4+2], t.z, pd);
        pd = fmaf(qpart[e4*4+3], t.w, pd);
    }
    pd += __shfl_xor(pd, 1);
    pd += __shfl_xor(pd, 2);
    float denom = pd;

    __syncthreads();   // K/V staged

    // Intra-chunk causal part. Wave-uniform trip count: rows in a wave are
    // [16w, 16w+16) so (i|15)+1 is identical across the wave's 64 lanes.
    const int Jmax = (i | 15) + 1;
#pragma unroll 1
    for (int j = 0; j < Jmax; ++j) {
        float p = 0.0f;
#pragma unroll
        for (int e4 = 0; e4 < 4; ++e4) {
            float4 kk = *(const float4*)(&Kl[j][cols + e4*4]);
            p = fmaf(qpart[e4*4+0], kk.x, p);
            p = fmaf(qpart[e4*4+1], kk.y, p);
            p = fmaf(qpart[e4*4+2], kk.z, p);
            p = fmaf(qpart[e4*4+3], kk.w, p);
        }
        p += __shfl_xor(p, 1);
        p += __shfl_xor(p, 2);               // full q.k_j in all 4 quad lanes
        const float a = (j <= i) ? p : 0.0f; // causal mask
        denom += a;
#pragma unroll
        for (int e4 = 0; e4 < 4; ++e4) {
            float4 vv = *(const float4*)(&Vl[j][cols + e4*4]);
            acc[e4*4+0] = fmaf(a, vv.x, acc[e4*4+0]);
            acc[e4*4+1] = fmaf(a, vv.y, acc[e4*4+1]);
            acc[e4*4+2] = fmaf(a, vv.z, acc[e4*4+2]);
            acc[e4*4+3] = fmaf(a, vv.w, acc[e4*4+3]);
        }
    }

    const float rn = 1.0f / denom;
    float* op = out + (((size_t)b*SS + s)*HH + h)*DD + cols;
#pragma unroll
    for (int e4 = 0; e4 < 4; ++e4) {
        float4 o = make_float4(acc[e4*4+0]*rn, acc[e4*4+1]*rn,
                               acc[e4*4+2]*rn, acc[e4*4+3]*rn);
        *(float4*)(op + e4*4) = o;
    }
}

// ---------------------------------------------------------------------------
extern "C" void kernel_launch(void* const* d_in, const int* in_sizes, int n_in,
                              void* d_out, int out_size, void* d_ws, size_t ws_size,
                              hipStream_t stream) {
    const float* qk = (const float*)d_in[0];
    const float* v  = (const float*)d_in[1];
    float* out = (float*)d_out;
    float* ws  = (float*)d_ws;   // needs BHN*NCH*RECF*4 = ~8.5 MB

    k_chunksum<<<dim3(BHN*NCH), dim3(256), 0, stream>>>(qk, v, ws);
    k_scan    <<<dim3(BHN*17),  dim3(256), 0, stream>>>(ws);
    k_out     <<<dim3(BHN*NCH), dim3(512), 0, stream>>>(qk, v, ws, out);
}

// Round 2
// 52.003 us; speedup vs baseline: 2.6114x; 2.6114x over previous
//
#include <hip/hip_runtime.h>

// Problem constants (B,S,H,D fixed by the reference)
#define BB   2
#define SS   2048
#define HH   16
#define DD   64
#define CC   128              // chunk length
#define NCH  (SS/CC)          // 16 chunks per (b,h)
#define RECF (DD*DD + DD)     // 4160 floats per (b,h,chunk) record: KV sum + ksum
#define BHN  (BB*HH)          // 32

typedef __attribute__((ext_vector_type(8))) short short8;
typedef __attribute__((ext_vector_type(4))) float f32x4;

__device__ __forceinline__ float elu1(float x) {
    return x > 0.0f ? x + 1.0f : __expf(x);
}

__device__ __forceinline__ short f2bf(float f) {
    union { float f; unsigned u; } x; x.f = f;
    unsigned r = x.u + 0x7FFFu + ((x.u >> 16) & 1u);   // RNE
    return (short)(r >> 16);
}

// ---------------------------------------------------------------------------
// Kernel 1: per-chunk KV outer-product sums and k sums (unchanged from R1).
// ---------------------------------------------------------------------------
__global__ __launch_bounds__(256) void k_chunksum(const float* __restrict__ qk,
                                                  const float* __restrict__ v,
                                                  float* __restrict__ ws) {
    const int blk = blockIdx.x;
    const int c   = blk % NCH;
    const int bh  = blk / NCH;
    const int b = bh / HH, h = bh % HH;
    const int tid = threadIdx.x;
    const int d   = tid >> 2;
    const int sub = tid & 3;

    __shared__ float kt[32][DD];
    __shared__ float vt[32][DD];

    float st[16];
#pragma unroll
    for (int e = 0; e < 16; ++e) st[e] = 0.0f;
    float ks = 0.0f;

#pragma unroll 1
    for (int t = 0; t < CC/32; ++t) {
        const int s0 = c*CC + t*32;
#pragma unroll
        for (int l = 0; l < 2; ++l) {
            const int idx  = tid + l*256;
            const int row  = idx >> 4;
            const int col4 = (idx & 15) * 4;
            const int s = s0 + row;
            float4 kq = *(const float4*)(qk + ((((size_t)b*SS + s)*2 + 1)*HH + h)*DD + col4);
            kq.x = elu1(kq.x); kq.y = elu1(kq.y); kq.z = elu1(kq.z); kq.w = elu1(kq.w);
            *(float4*)(&kt[row][col4]) = kq;
            *(float4*)(&vt[row][col4]) =
                *(const float4*)(v + (((size_t)b*SS + s)*HH + h)*DD + col4);
        }
        __syncthreads();
#pragma unroll 4
        for (int s = 0; s < 32; ++s) {
            const float kd = kt[s][d];
            ks += kd;
#pragma unroll
            for (int e = 0; e < 16; ++e)
                st[e] = fmaf(kd, vt[s][sub*16 + e], st[e]);
        }
        __syncthreads();
    }

    float* rec = ws + (size_t)(bh*NCH + c) * RECF;
#pragma unroll
    for (int e4 = 0; e4 < 4; ++e4) {
        float4 o = make_float4(st[e4*4], st[e4*4+1], st[e4*4+2], st[e4*4+3]);
        *(float4*)(rec + d*DD + sub*16 + e4*4) = o;
    }
    if (sub == 0) rec[DD*DD + d] = ks;
}

// ---------------------------------------------------------------------------
// Kernel 2: exclusive prefix scan over chunks (unchanged from R1).
// ---------------------------------------------------------------------------
__global__ __launch_bounds__(256) void k_scan(float* __restrict__ ws) {
    const int bh   = blockIdx.x / 17;
    const int elem = (blockIdx.x % 17) * 256 + threadIdx.x;
    if (elem >= RECF) return;
    float pref = 0.0f;
#pragma unroll 1
    for (int c = 0; c < NCH; ++c) {
        float* p = ws + (size_t)(bh*NCH + c)*RECF + elem;
        const float val = *p;
        *p = pref;
        pref += val;
    }
}

// ---------------------------------------------------------------------------
// Kernel 3 (MFMA): per (b,h,chunk), 512 threads = 8 waves, wave w owns output
// rows [16w,16w+16).  O = [S | Q] . [V ; State]  with K = 128+64, where
// S = mask(Q K^T).  V gets a ones-column and State a ksum-column so that
// column 64 of O is the softmax-free denominator q.k_cum.
// LDS strides padded to 2-way bank aliasing (free): 72 / 136 shorts.
// ---------------------------------------------------------------------------
__global__ __launch_bounds__(512) void k_out_mfma(const float* __restrict__ qk,
                                                  const float* __restrict__ v,
                                                  const float* __restrict__ ws,
                                                  float* __restrict__ out) {
    const int blk = blockIdx.x;
    const int c   = blk % NCH;
    const int bh  = blk / NCH;
    const int b = bh / HH, h = bh % HH;
    const int tid = threadIdx.x;
    const int w   = tid >> 6;
    const int l   = tid & 63;
    const int l15 = l & 15;
    const int g   = l >> 4;          // 16-lane group 0..3

    __shared__ short Kb [128][72];   // K chunk, elu1, bf16   (18 KB)
    __shared__ short Sb [128][136];  // masked scores bf16    (34 KB)
    __shared__ short VbT[ 80][136];  // V^T (+ones col 64)    (21.25 KB)
    __shared__ short StT[ 80][72];   // State^T (+ksum col 64)(11.25 KB)

    const float* rec = ws + (size_t)(bh*NCH + c) * RECF;

    // ---- stage K (elu1->bf16) and V^T ----
#pragma unroll
    for (int it = 0; it < 4; ++it) {
        const int f    = tid + it*512;      // float4 index 0..2047
        const int row  = f >> 4;            // 0..127
        const int col4 = (f & 15) * 4;
        const int s = c*CC + row;
        float4 kq = *(const float4*)(qk + ((((size_t)b*SS + s)*2 + 1)*HH + h)*DD + col4);
        short4 kb;
        kb.x = f2bf(elu1(kq.x)); kb.y = f2bf(elu1(kq.y));
        kb.z = f2bf(elu1(kq.z)); kb.w = f2bf(elu1(kq.w));
        *(short4*)(&Kb[row][col4]) = kb;
        float4 vv = *(const float4*)(v + (((size_t)b*SS + s)*HH + h)*DD + col4);
        VbT[col4+0][row] = f2bf(vv.x);
        VbT[col4+1][row] = f2bf(vv.y);
        VbT[col4+2][row] = f2bf(vv.z);
        VbT[col4+3][row] = f2bf(vv.w);
    }
    // ones column (denominator trick) + zero pad cols 65..79 of V^T
    if (tid < 128) VbT[64][tid] = (short)0x3F80;         // bf16(1.0)
    for (int idx = tid; idx < 15*128; idx += 512) {
        VbT[65 + idx/128][idx & 127] = 0;
    }
    // ---- stage State^T (bf16) + ksum col ----
#pragma unroll
    for (int it = 0; it < 8; ++it) {
        const int idx = tid + it*512;       // 0..4095
        const int d   = idx >> 6;
        const int t   = idx & 63;
        StT[t][d] = f2bf(rec[idx]);
    }
    if (tid < 64) StT[64][tid] = f2bf(rec[DD*DD + tid]);
    for (int idx = tid; idx < 15*64; idx += 512) {
        StT[65 + idx/64][idx & 63] = 0;
    }

    // ---- Q fragments straight from global (reused by both matmuls) ----
    const int qrow = 16*w + l15;
    const float* qp = qk + ((((size_t)b*SS + (c*CC + qrow))*2 + 0)*HH + h)*DD;
    short8 aq[2];
#pragma unroll
    for (int ks = 0; ks < 2; ++ks) {
        const int k0 = 32*ks + 8*g;
        float4 t0 = *(const float4*)(qp + k0);
        float4 t1 = *(const float4*)(qp + k0 + 4);
        short8 a;
        a[0] = f2bf(elu1(t0.x)); a[1] = f2bf(elu1(t0.y));
        a[2] = f2bf(elu1(t0.z)); a[3] = f2bf(elu1(t0.w));
        a[4] = f2bf(elu1(t1.x)); a[5] = f2bf(elu1(t1.y));
        a[6] = f2bf(elu1(t1.z)); a[7] = f2bf(elu1(t1.w));
        aq[ks] = a;
    }

    __syncthreads();

    // ---- S = mask(Q K^T), written to Sb as bf16 ----
    const int rowb = 16*w + 4*g;            // C-layout row base for this lane
#pragma unroll
    for (int tc = 0; tc < 8; ++tc) {
        f32x4 acc = {0.f, 0.f, 0.f, 0.f};
#pragma unroll
        for (int ks = 0; ks < 2; ++ks) {
            short8 bk = *(const short8*)(&Kb[16*tc + l15][32*ks + 8*g]);
            acc = __builtin_amdgcn_mfma_f32_16x16x32_bf16(aq[ks], bk, acc, 0, 0, 0);
        }
        const int colg = 16*tc + l15;
#pragma unroll
        for (int e = 0; e < 4; ++e) {
            const float sv = (colg <= rowb + e) ? acc[e] : 0.0f;
            Sb[rowb + e][colg] = f2bf(sv);
        }
    }

    __syncthreads();

    // ---- O = S.V + Q.State  (5th col-tile = denominator column) ----
    f32x4 acc[5];
#pragma unroll
    for (int t = 0; t < 5; ++t) acc[t] = (f32x4){0.f, 0.f, 0.f, 0.f};

#pragma unroll
    for (int kj = 0; kj < 4; ++kj) {
        short8 as = *(const short8*)(&Sb[16*w + l15][32*kj + 8*g]);
#pragma unroll
        for (int tc = 0; tc < 5; ++tc) {
            short8 bv = *(const short8*)(&VbT[16*tc + l15][32*kj + 8*g]);
            acc[tc] = __builtin_amdgcn_mfma_f32_16x16x32_bf16(as, bv, acc[tc], 0, 0, 0);
        }
    }
#pragma unroll
    for (int kd = 0; kd < 2; ++kd) {
#pragma unroll
        for (int tc = 0; tc < 5; ++tc) {
            short8 bs = *(const short8*)(&StT[16*tc + l15][32*kd + 8*g]);
            acc[tc] = __builtin_amdgcn_mfma_f32_16x16x32_bf16(aq[kd], bs, acc[tc], 0, 0, 0);
        }
    }

    // ---- epilogue: denom broadcast within 16-lane group, normalize, store ----
    const int src = l & 48;                 // lane with l15==0 in this group
    float rn[4];
#pragma unroll
    for (int e = 0; e < 4; ++e) {
        const float dn = __shfl(acc[4][e], src);
        rn[e] = 1.0f / dn;
    }
    const int rowg = c*CC + rowb;           // global sequence row base
#pragma unroll
    for (int e = 0; e < 4; ++e) {
        float* orow = out + (((size_t)b*SS + rowg + e)*HH + h)*DD + l15;
#pragma unroll
        for (int tc = 0; tc < 4; ++tc) {
            orow[16*tc] = acc[tc][e] * rn[e];
        }
    }
}

// ---------------------------------------------------------------------------
extern "C" void kernel_launch(void* const* d_in, const int* in_sizes, int n_in,
                              void* d_out, int out_size, void* d_ws, size_t ws_size,
                              hipStream_t stream) {
    const float* qk = (const float*)d_in[0];
    const float* v  = (const float*)d_in[1];
    float* out = (float*)d_out;
    float* ws  = (float*)d_ws;   // needs BHN*NCH*RECF*4 = ~8.5 MB

    k_chunksum<<<dim3(BHN*NCH), dim3(256), 0, stream>>>(qk, v, ws);
    k_scan    <<<dim3(BHN*17),  dim3(256), 0, stream>>>(ws);
    k_out_mfma<<<dim3(BHN*NCH), dim3(512), 0, stream>>>(qk, v, ws, out);
}

// Round 4
// 34.534 us; speedup vs baseline: 3.9324x; 1.5059x over previous
//
#include <hip/hip_runtime.h>

// Problem constants (B,S,H,D fixed by the reference)
#define BB   2
#define SS   2048
#define HH   16
#define DD   64
#define CC   128               // chunk length
#define NCH  (SS/CC)           // 16 chunks per (b,h)
#define RECF (DD*DD + DD)      // 4160 floats per record: State^T rows 0..63 + ksum row 64
#define BHN  (BB*HH)           // 32
#define NCHK (BHN*NCH)         // 512 chunk-blocks

typedef __attribute__((ext_vector_type(8))) short short8;
typedef __attribute__((ext_vector_type(4))) float f32x4;

// XOR swizzle of the s-index (units of 8 elements) by LDS row — kills the
// transposed-write bank conflicts while keeping b128 reads contiguous.
#define SW(r) ((((r) >> 3) & 7) << 3)

__device__ __forceinline__ float elu1(float x) {
    return x > 0.0f ? x + 1.0f : __expf(x);
}
__device__ __forceinline__ short f2bf(float f) {
    union { float f; unsigned u; } x; x.f = f;
    unsigned r = x.u + 0x7FFFu + ((x.u >> 16) & 1u);   // RNE
    return (short)(r >> 16);
}

// ---------------------------------------------------------------------------
// Kernel 1 (MFMA): per (b,h,chunk): State^T(+ksum row) = [V^T; ones] . K,
// K-dim = 128 (chunk). Also dumps bf16 K (row-major, elu1 applied) and V^T
// to ws so kernel 3 stages with pure coalesced copies.
// ---------------------------------------------------------------------------
__global__ __launch_bounds__(256) void k_chunksum_mfma(const float* __restrict__ qk,
                                                       const float* __restrict__ v,
                                                       float* __restrict__ rec_g,
                                                       short* __restrict__ kbuf,
                                                       short* __restrict__ vtbuf) {
    const int blk = blockIdx.x;
    const int c   = blk % NCH;
    const int bh  = blk / NCH;
    const int b = bh / HH, h = bh % HH;
    const int tid = threadIdx.x;
    const int w   = tid >> 6;
    const int l   = tid & 63;
    const int l15 = l & 15;
    const int g   = l >> 4;

    __shared__ short KT[64][136];   // K^T, swizzled cols   (17 KB)
    __shared__ short VT[80][136];   // V^T + ones row 64    (21.25 KB)

    short* kb_g = kbuf  + (size_t)blk * (CC*DD);
    short* vt_g = vtbuf + (size_t)blk * (DD*CC);

#pragma unroll
    for (int it = 0; it < 8; ++it) {
        const int f    = tid + it*256;      // float4 index 0..2047
        const int row  = f >> 4;            // s in chunk, 0..127
        const int col4 = (f & 15) * 4;      // d
        const int s = c*CC + row;
        float4 kq = *(const float4*)(qk + ((((size_t)b*SS + s)*2 + 1)*HH + h)*DD + col4);
        short4 kb;
        kb.x = f2bf(elu1(kq.x)); kb.y = f2bf(elu1(kq.y));
        kb.z = f2bf(elu1(kq.z)); kb.w = f2bf(elu1(kq.w));
        *(short4*)(kb_g + row*DD + col4) = kb;
        KT[col4+0][row ^ SW(col4+0)] = kb.x;
        KT[col4+1][row ^ SW(col4+1)] = kb.y;
        KT[col4+2][row ^ SW(col4+2)] = kb.z;
        KT[col4+3][row ^ SW(col4+3)] = kb.w;
        float4 vv = *(const float4*)(v + (((size_t)b*SS + s)*HH + h)*DD + col4);
        short4 vb;
        vb.x = f2bf(vv.x); vb.y = f2bf(vv.y); vb.z = f2bf(vv.z); vb.w = f2bf(vv.w);
        VT[col4+0][row ^ SW(col4+0)] = vb.x;
        VT[col4+1][row ^ SW(col4+1)] = vb.y;
        VT[col4+2][row ^ SW(col4+2)] = vb.z;
        VT[col4+3][row ^ SW(col4+3)] = vb.w;
    }
    if (tid < 128) VT[64][tid] = (short)0x3F80;   // ones row (SW(64)==0)
    __syncthreads();

    // dump V^T rows 0..63 (bf16, unswizzled order) for kernel 3
    // 64 rows x 128 cols = 1024 short8 units -> 4 iterations of 256 threads
#pragma unroll
    for (int it = 0; it < 4; ++it) {
        const int u  = tid + it*256;        // short8 unit 0..1023
        const int t  = u >> 4, s8 = (u & 15) * 8;
        short8 val = *(const short8*)(&VT[t][s8 ^ SW(t)]);
        *(short8*)(vt_g + t*CC + s8) = val;
    }

    // MFMA: C[t][d] = sum_s VTrow[t][s] * K[s][d]; wave w: d-tile = w
    f32x4 acc[5];
#pragma unroll
    for (int rt = 0; rt < 5; ++rt) acc[rt] = (f32x4){0.f,0.f,0.f,0.f};
    const int krow = 16*w + l15;            // B col index d
#pragma unroll
    for (int ks = 0; ks < 4; ++ks) {
        const int cb = 32*ks + 8*g;
        short8 bk = *(const short8*)(&KT[krow][cb ^ SW(krow)]);
#pragma unroll
        for (int rt = 0; rt < 5; ++rt) {
            const int arow = 16*rt + l15;
            short8 a = *(const short8*)(&VT[arow][cb ^ SW(arow)]);
            acc[rt] = __builtin_amdgcn_mfma_f32_16x16x32_bf16(a, bk, acc[rt], 0, 0, 0);
        }
    }

    float* rec = rec_g + (size_t)blk * RECF;
#pragma unroll
    for (int rt = 0; rt < 4; ++rt)
#pragma unroll
        for (int e = 0; e < 4; ++e)
            rec[(16*rt + 4*g + e)*DD + 16*w + l15] = acc[rt][e];
    if (g == 0) rec[4096 + 16*w + l15] = acc[4][0];   // ksum row (row 64)
}

// ---------------------------------------------------------------------------
// Kernel 2: exclusive prefix scan over chunks (elementwise, layout-agnostic).
// ---------------------------------------------------------------------------
__global__ __launch_bounds__(256) void k_scan(float* __restrict__ rec_g) {
    const int bh   = blockIdx.x / 17;
    const int elem = (blockIdx.x % 17) * 256 + threadIdx.x;
    if (elem >= RECF) return;
    float pref = 0.0f;
#pragma unroll 1
    for (int c = 0; c < NCH; ++c) {
        float* p = rec_g + (size_t)(bh*NCH + c)*RECF + elem;
        const float val = *p;
        *p = pref;
        pref += val;
    }
}

// ---------------------------------------------------------------------------
// Kernel 3 (MFMA): O = [S | Q] . [V;ones ; State^T;ksum], S = mask(Q K^T).
// Column 64 = denominator. All staging is coalesced b128 copies of bf16
// produced by kernel 1. StT aliases Kb's LDS (dead after QK^T) -> 73.25 KB
// -> 2 blocks/CU. rec loads issued before the S.V MFMA block to hide latency.
// ---------------------------------------------------------------------------
__global__ __launch_bounds__(512) void k_out_mfma(const float* __restrict__ qk,
                                                  const float* __restrict__ rec_g,
                                                  const short* __restrict__ kbuf,
                                                  const short* __restrict__ vtbuf,
                                                  float* __restrict__ out) {
    const int blk = blockIdx.x;
    const int c   = blk % NCH;
    const int bh  = blk / NCH;
    const int b = bh / HH, h = bh % HH;
    const int tid = threadIdx.x;
    const int w   = tid >> 6;
    const int l   = tid & 63;
    const int l15 = l & 15;
    const int g   = l >> 4;

    __shared__ __align__(16) char smem[75008];
    short (*Kb)[72]   = (short(*)[72])smem;                     // 18432 B (phase 1)
    short (*StT)[72]  = (short(*)[72])smem;                     // 11520 B (phase 2, aliases Kb)
    short (*Sb)[136]  = (short(*)[136])(smem + 18432);          // 34816 B
    short (*VbT)[136] = (short(*)[136])(smem + 18432 + 34816);  // 21760 B

    const short* kb_g = kbuf  + (size_t)blk * (CC*DD);
    const short* vt_g = vtbuf + (size_t)blk * (DD*CC);
    const float* rec  = rec_g + (size_t)blk * RECF;

    // ---- stage Kb [128][64]: 1024 short8 units ----
#pragma unroll
    for (int it = 0; it < 2; ++it) {
        const int u = tid + it*512;         // 0..1023
        const int row = u >> 3, col8 = (u & 7) * 8;
        *(short8*)(&Kb[row][col8]) = *(const short8*)(kb_g + row*DD + col8);
    }
    // ---- stage VbT rows 0..63: 64x128 = 1024 short8 units ----
#pragma unroll
    for (int it = 0; it < 2; ++it) {
        const int u = tid + it*512;         // 0..1023
        const int t = u >> 4, s8 = (u & 15) * 8;
        *(short8*)(&VbT[t][s8]) = *(const short8*)(vt_g + t*CC + s8);
    }
    if (tid < 128) VbT[64][tid] = (short)0x3F80;   // ones row

    // ---- Q fragments from global (elu1 -> bf16), reused by both matmuls ----
    const int qrow = 16*w + l15;
    const float* qp = qk + ((((size_t)b*SS + (c*CC + qrow))*2 + 0)*HH + h)*DD;
    short8 aq[2];
#pragma unroll
    for (int ks = 0; ks < 2; ++ks) {
        const int k0 = 32*ks + 8*g;
        float4 t0 = *(const float4*)(qp + k0);
        float4 t1 = *(const float4*)(qp + k0 + 4);
        short8 a;
        a[0] = f2bf(elu1(t0.x)); a[1] = f2bf(elu1(t0.y));
        a[2] = f2bf(elu1(t0.z)); a[3] = f2bf(elu1(t0.w));
        a[4] = f2bf(elu1(t1.x)); a[5] = f2bf(elu1(t1.y));
        a[6] = f2bf(elu1(t1.z)); a[7] = f2bf(elu1(t1.w));
        aq[ks] = a;
    }
    __syncthreads();

    // ---- S = mask(Q K^T) -> Sb (bf16) ----
    const int rowb = 16*w + 4*g;
#pragma unroll
    for (int tc = 0; tc < 8; ++tc) {
        f32x4 acc = {0.f,0.f,0.f,0.f};
#pragma unroll
        for (int ks = 0; ks < 2; ++ks) {
            short8 bk = *(const short8*)(&Kb[16*tc + l15][32*ks + 8*g]);
            acc = __builtin_amdgcn_mfma_f32_16x16x32_bf16(aq[ks], bk, acc, 0, 0, 0);
        }
        const int colg = 16*tc + l15;
#pragma unroll
        for (int e = 0; e < 4; ++e) {
            const float sv = (colg <= rowb + e) ? acc[e] : 0.0f;
            Sb[rowb + e][colg] = f2bf(sv);
        }
    }
    __syncthreads();   // Kb dead from here; Sb ready

    // ---- issue rec (State^T, scanned) loads; they drain under the S.V MFMAs
    float4 r0 = *(const float4*)(rec + tid*8);
    float4 r1 = *(const float4*)(rec + tid*8 + 4);
    float4 r2 = {0,0,0,0}, r3 = {0,0,0,0};
    if (tid < 8) {
        r2 = *(const float4*)(rec + 4096 + tid*8);
        r3 = *(const float4*)(rec + 4096 + tid*8 + 4);
    }

    // ---- O = S.V (5 col-tiles; tile 4 col 64 = denominator) ----
    f32x4 acc[5];
#pragma unroll
    for (int t = 0; t < 5; ++t) acc[t] = (f32x4){0.f,0.f,0.f,0.f};
#pragma unroll
    for (int kj = 0; kj < 4; ++kj) {
        short8 as = *(const short8*)(&Sb[16*w + l15][32*kj + 8*g]);
#pragma unroll
        for (int tc = 0; tc < 5; ++tc) {
            short8 bv = *(const short8*)(&VbT[16*tc + l15][32*kj + 8*g]);
            acc[tc] = __builtin_amdgcn_mfma_f32_16x16x32_bf16(as, bv, acc[tc], 0, 0, 0);
        }
    }

    // ---- write StT (into Kb's space): rec is State^T layout -> direct copy
    {
        short8 sv;
        sv[0] = f2bf(r0.x); sv[1] = f2bf(r0.y); sv[2] = f2bf(r0.z); sv[3] = f2bf(r0.w);
        sv[4] = f2bf(r1.x); sv[5] = f2bf(r1.y); sv[6] = f2bf(r1.z); sv[7] = f2bf(r1.w);
        *(short8*)(&StT[tid >> 3][(tid & 7) * 8]) = sv;
        if (tid < 8) {
            short8 s2;
            s2[0] = f2bf(r2.x); s2[1] = f2bf(r2.y); s2[2] = f2bf(r2.z); s2[3] = f2bf(r2.w);
            s2[4] = f2bf(r3.x); s2[5] = f2bf(r3.y); s2[6] = f2bf(r3.z); s2[7] = f2bf(r3.w);
            *(short8*)(&StT[64][tid * 8]) = s2;
        }
    }
    __syncthreads();

    // ---- O += Q . State^T ----
#pragma unroll
    for (int kd = 0; kd < 2; ++kd) {
#pragma unroll
        for (int tc = 0; tc < 5; ++tc) {
            short8 bs = *(const short8*)(&StT[16*tc + l15][32*kd + 8*g]);
            acc[tc] = __builtin_amdgcn_mfma_f32_16x16x32_bf16(aq[kd], bs, acc[tc], 0, 0, 0);
        }
    }

    // ---- epilogue: broadcast denom, normalize, store ----
    const int src = l & 48;
    float rn[4];
#pragma unroll
    for (int e = 0; e < 4; ++e) rn[e] = 1.0f / __shfl(acc[4][e], src);
    const int rowg = c*CC + rowb;
#pragma unroll
    for (int e = 0; e < 4; ++e) {
        float* orow = out + (((size_t)b*SS + rowg + e)*HH + h)*DD + l15;
#pragma unroll
        for (int tc = 0; tc < 4; ++tc) orow[16*tc] = acc[tc][e] * rn[e];
    }
}

// ---------------------------------------------------------------------------
extern "C" void kernel_launch(void* const* d_in, const int* in_sizes, int n_in,
                              void* d_out, int out_size, void* d_ws, size_t ws_size,
                              hipStream_t stream) {
    const float* qk = (const float*)d_in[0];
    const float* v  = (const float*)d_in[1];
    float* out = (float*)d_out;
    float* ws  = (float*)d_ws;

    float* rec_g = ws;                                        // 512*4160 fp32 = 8.52 MB
    short* kbuf  = (short*)(ws + (size_t)NCHK * RECF);        // 512*8192 bf16 = 8.39 MB
    short* vtbuf = kbuf + (size_t)NCHK * (CC*DD);             // 512*8192 bf16 = 8.39 MB

    k_chunksum_mfma<<<dim3(NCHK),   dim3(256), 0, stream>>>(qk, v, rec_g, kbuf, vtbuf);
    k_scan         <<<dim3(BHN*17), dim3(256), 0, stream>>>(rec_g);
    k_out_mfma     <<<dim3(NCHK),   dim3(512), 0, stream>>>(qk, rec_g, kbuf, vtbuf, out);
}

// Round 5
// 32.178 us; speedup vs baseline: 4.2203x; 1.0732x over previous
//
#include <hip/hip_runtime.h>

// Problem constants (B,S,H,D fixed by the reference)
#define BB   2
#define SS   2048
#define HH   16
#define DD   64
#define CC   128               // chunk length
#define NCH  (SS/CC)           // 16 chunks per (b,h)
#define RECF (DD*DD + DD)      // 4160 floats per record: State^T rows 0..63 + ksum row 64
#define BHN  (BB*HH)           // 32
#define NCHK (BHN*NCH)         // 512 chunk-blocks

typedef __attribute__((ext_vector_type(8))) short short8;
typedef __attribute__((ext_vector_type(4))) float f32x4;

// XOR swizzle of the s-index (units of 8 elements) by LDS row — kills the
// transposed-write bank conflicts while keeping b128 reads contiguous.
#define SW(r) ((((r) >> 3) & 7) << 3)

__device__ __forceinline__ float elu1(float x) {
    return x > 0.0f ? x + 1.0f : __expf(x);
}
__device__ __forceinline__ short f2bf(float f) {
    union { float f; unsigned u; } x; x.f = f;
    unsigned r = x.u + 0x7FFFu + ((x.u >> 16) & 1u);   // RNE
    return (short)(r >> 16);
}

// ---------------------------------------------------------------------------
// Kernel 1 (MFMA): per (b,h,chunk): State^T(+ksum row) = [V^T; ones] . K.
// Also dumps bf16 K (row-major, elu1) and V^T to ws for kernel 3's staging.
// 512 threads = 8 waves (4 waves/SIMD at 2 blocks/CU): wave w -> d-tile w&3,
// row-tile half w>>2 (half 0: rt 0..2, half 1: rt 3..4).
// ---------------------------------------------------------------------------
__global__ __launch_bounds__(512) void k_chunksum_mfma(const float* __restrict__ qk,
                                                       const float* __restrict__ v,
                                                       float* __restrict__ rec_g,
                                                       short* __restrict__ kbuf,
                                                       short* __restrict__ vtbuf) {
    const int blk = blockIdx.x;
    const int c   = blk % NCH;
    const int bh  = blk / NCH;
    const int b = bh / HH, h = bh % HH;
    const int tid = threadIdx.x;
    const int w   = tid >> 6;
    const int l   = tid & 63;
    const int l15 = l & 15;
    const int g   = l >> 4;

    __shared__ short KT[64][136];   // K^T, swizzled cols   (17 KB)
    __shared__ short VT[80][136];   // V^T + ones row 64    (21.25 KB; rows 65+ garbage, discarded)

    short* kb_g = kbuf  + (size_t)blk * (CC*DD);
    short* vt_g = vtbuf + (size_t)blk * (DD*CC);

#pragma unroll
    for (int it = 0; it < 4; ++it) {
        const int f    = tid + it*512;      // float4 index 0..2047
        const int row  = f >> 4;            // s in chunk, 0..127
        const int col4 = (f & 15) * 4;      // d
        const int s = c*CC + row;
        float4 kq = *(const float4*)(qk + ((((size_t)b*SS + s)*2 + 1)*HH + h)*DD + col4);
        short4 kb;
        kb.x = f2bf(elu1(kq.x)); kb.y = f2bf(elu1(kq.y));
        kb.z = f2bf(elu1(kq.z)); kb.w = f2bf(elu1(kq.w));
        *(short4*)(kb_g + row*DD + col4) = kb;
        KT[col4+0][row ^ SW(col4+0)] = kb.x;
        KT[col4+1][row ^ SW(col4+1)] = kb.y;
        KT[col4+2][row ^ SW(col4+2)] = kb.z;
        KT[col4+3][row ^ SW(col4+3)] = kb.w;
        float4 vv = *(const float4*)(v + (((size_t)b*SS + s)*HH + h)*DD + col4);
        short4 vb;
        vb.x = f2bf(vv.x); vb.y = f2bf(vv.y); vb.z = f2bf(vv.z); vb.w = f2bf(vv.w);
        VT[col4+0][row ^ SW(col4+0)] = vb.x;
        VT[col4+1][row ^ SW(col4+1)] = vb.y;
        VT[col4+2][row ^ SW(col4+2)] = vb.z;
        VT[col4+3][row ^ SW(col4+3)] = vb.w;
    }
    if (tid < 128) VT[64][tid] = (short)0x3F80;   // ones row (SW(64)==0)
    __syncthreads();

    // dump V^T rows 0..63 (bf16, unswizzled order): 1024 short8 units
#pragma unroll
    for (int it = 0; it < 2; ++it) {
        const int u  = tid + it*512;        // short8 unit 0..1023
        const int t  = u >> 4, s8 = (u & 15) * 8;
        short8 val = *(const short8*)(&VT[t][s8 ^ SW(t)]);
        *(short8*)(vt_g + t*CC + s8) = val;
    }

    // MFMA: C[t][d] = sum_s VT[t][s] * K[s][d]
    const int dtile = w & 3;
    const int half  = w >> 2;              // 0: rt 0..2, 1: rt 3..4
    const int nrt   = half ? 2 : 3;
    const int rt0   = half ? 3 : 0;
    f32x4 acc[3];
#pragma unroll
    for (int i = 0; i < 3; ++i) acc[i] = (f32x4){0.f,0.f,0.f,0.f};
    const int krow = 16*dtile + l15;       // B col index d
#pragma unroll
    for (int ks = 0; ks < 4; ++ks) {
        const int cb = 32*ks + 8*g;
        short8 bk = *(const short8*)(&KT[krow][cb ^ SW(krow)]);
#pragma unroll
        for (int i = 0; i < 3; ++i) {
            if (i < nrt) {
                const int arow = 16*(rt0 + i) + l15;
                short8 a = *(const short8*)(&VT[arow][cb ^ SW(arow)]);
                acc[i] = __builtin_amdgcn_mfma_f32_16x16x32_bf16(a, bk, acc[i], 0, 0, 0);
            }
        }
    }

    float* rec = rec_g + (size_t)blk * RECF;
#pragma unroll
    for (int i = 0; i < 3; ++i) {
        if (i < nrt) {
            const int rt = rt0 + i;
            if (rt < 4) {
#pragma unroll
                for (int e = 0; e < 4; ++e)
                    rec[(16*rt + 4*g + e)*DD + 16*dtile + l15] = acc[i][e];
            } else if (g == 0) {
                rec[4096 + 16*dtile + l15] = acc[i][0];   // ksum row (row 64)
            }
        }
    }
}

// ---------------------------------------------------------------------------
// Kernel 2: exclusive prefix scan over chunks. Fully unrolled: all 16 chunk
// loads in flight (address-independent), then prefix in regs, bf16 stores.
// grid = 512 blocks (bh = blk>>4, element slice = blk&15 -> 260 elems).
// ---------------------------------------------------------------------------
__global__ __launch_bounds__(256) void k_scan(const float* __restrict__ rec_g,
                                              short* __restrict__ stp_g) {
    const int bh    = blockIdx.x >> 4;
    const int slice = blockIdx.x & 15;
#pragma unroll 1
    for (int ee = threadIdx.x; ee < 260; ee += 256) {
        const int elem = slice*260 + ee;
        float vals[16];
#pragma unroll
        for (int c = 0; c < 16; ++c)
            vals[c] = rec_g[(size_t)(bh*NCH + c)*RECF + elem];
        float pref = 0.0f;
#pragma unroll
        for (int c = 0; c < 16; ++c) {
            stp_g[(size_t)(bh*NCH + c)*RECF + elem] = f2bf(pref);
            pref += vals[c];
        }
    }
}

// ---------------------------------------------------------------------------
// Kernel 3 (MFMA): O = [S | Q] . [V;ones ; State^T;ksum], S = mask(Q K^T).
// Column 64 = denominator. All staging is coalesced b128 copies of bf16.
// StT aliases Kb's LDS (dead after QK^T) -> 2 blocks/CU.
// ---------------------------------------------------------------------------
__global__ __launch_bounds__(512) void k_out_mfma(const float* __restrict__ qk,
                                                  const short* __restrict__ stp_g,
                                                  const short* __restrict__ kbuf,
                                                  const short* __restrict__ vtbuf,
                                                  float* __restrict__ out) {
    const int blk = blockIdx.x;
    const int c   = blk % NCH;
    const int bh  = blk / NCH;
    const int b = bh / HH, h = bh % HH;
    const int tid = threadIdx.x;
    const int w   = tid >> 6;
    const int l   = tid & 63;
    const int l15 = l & 15;
    const int g   = l >> 4;

    __shared__ __align__(16) char smem[75008];
    short (*Kb)[72]   = (short(*)[72])smem;                     // 18432 B (phase 1)
    short (*StT)[72]  = (short(*)[72])smem;                     // 9360 B used (phase 2, aliases Kb)
    short (*Sb)[136]  = (short(*)[136])(smem + 18432);          // 34816 B
    short (*VbT)[136] = (short(*)[136])(smem + 18432 + 34816);  // 21760 B

    const short* kb_g = kbuf  + (size_t)blk * (CC*DD);
    const short* vt_g = vtbuf + (size_t)blk * (DD*CC);
    const short* stp  = stp_g + (size_t)blk * RECF;

    // ---- stage Kb [128][64]: 1024 short8 units ----
#pragma unroll
    for (int it = 0; it < 2; ++it) {
        const int u = tid + it*512;         // 0..1023
        const int row = u >> 3, col8 = (u & 7) * 8;
        *(short8*)(&Kb[row][col8]) = *(const short8*)(kb_g + row*DD + col8);
    }
    // ---- stage VbT rows 0..63: 1024 short8 units ----
#pragma unroll
    for (int it = 0; it < 2; ++it) {
        const int u = tid + it*512;         // 0..1023
        const int t = u >> 4, s8 = (u & 15) * 8;
        *(short8*)(&VbT[t][s8]) = *(const short8*)(vt_g + t*CC + s8);
    }
    if (tid < 128) VbT[64][tid] = (short)0x3F80;   // ones row

    // ---- scanned-prefix (bf16) loads into regs; LDS-write deferred until
    //      Kb is dead (StT aliases it). 520 short8 units total.
    short8 st0 = *(const short8*)(stp + tid*8);
    short8 st1 = {};
    if (tid < 8) st1 = *(const short8*)(stp + 4096 + tid*8);

    // ---- Q fragments from global (elu1 -> bf16), reused by both matmuls ----
    const int qrow = 16*w + l15;
    const float* qp = qk + ((((size_t)b*SS + (c*CC + qrow))*2 + 0)*HH + h)*DD;
    short8 aq[2];
#pragma unroll
    for (int ks = 0; ks < 2; ++ks) {
        const int k0 = 32*ks + 8*g;
        float4 t0 = *(const float4*)(qp + k0);
        float4 t1 = *(const float4*)(qp + k0 + 4);
        short8 a;
        a[0] = f2bf(elu1(t0.x)); a[1] = f2bf(elu1(t0.y));
        a[2] = f2bf(elu1(t0.z)); a[3] = f2bf(elu1(t0.w));
        a[4] = f2bf(elu1(t1.x)); a[5] = f2bf(elu1(t1.y));
        a[6] = f2bf(elu1(t1.z)); a[7] = f2bf(elu1(t1.w));
        aq[ks] = a;
    }
    __syncthreads();

    // ---- S = mask(Q K^T) -> Sb (bf16) ----
    const int rowb = 16*w + 4*g;
#pragma unroll
    for (int tc = 0; tc < 8; ++tc) {
        f32x4 acc = {0.f,0.f,0.f,0.f};
#pragma unroll
        for (int ks = 0; ks < 2; ++ks) {
            short8 bk = *(const short8*)(&Kb[16*tc + l15][32*ks + 8*g]);
            acc = __builtin_amdgcn_mfma_f32_16x16x32_bf16(aq[ks], bk, acc, 0, 0, 0);
        }
        const int colg = 16*tc + l15;
#pragma unroll
        for (int e = 0; e < 4; ++e) {
            const float sv = (colg <= rowb + e) ? acc[e] : 0.0f;
            Sb[rowb + e][colg] = f2bf(sv);
        }
    }
    __syncthreads();   // Kb dead from here; Sb ready

    // ---- write StT (into Kb's space): direct bf16 copy ----
    *(short8*)(&StT[tid >> 3][(tid & 7) * 8]) = st0;
    if (tid < 8) *(short8*)(&StT[64][tid * 8]) = st1;

    // ---- O = S.V (5 col-tiles; tile 4 col 64 = denominator) ----
    f32x4 acc[5];
#pragma unroll
    for (int t = 0; t < 5; ++t) acc[t] = (f32x4){0.f,0.f,0.f,0.f};
#pragma unroll
    for (int kj = 0; kj < 4; ++kj) {
        short8 as = *(const short8*)(&Sb[16*w + l15][32*kj + 8*g]);
#pragma unroll
        for (int tc = 0; tc < 5; ++tc) {
            short8 bv = *(const short8*)(&VbT[16*tc + l15][32*kj + 8*g]);
            acc[tc] = __builtin_amdgcn_mfma_f32_16x16x32_bf16(as, bv, acc[tc], 0, 0, 0);
        }
    }
    __syncthreads();   // StT writes visible

    // ---- O += Q . State^T ----
#pragma unroll
    for (int kd = 0; kd < 2; ++kd) {
#pragma unroll
        for (int tc = 0; tc < 5; ++tc) {
            short8 bs = *(const short8*)(&StT[16*tc + l15][32*kd + 8*g]);
            acc[tc] = __builtin_amdgcn_mfma_f32_16x16x32_bf16(aq[kd], bs, acc[tc], 0, 0, 0);
        }
    }

    // ---- epilogue: broadcast denom, normalize, store ----
    const int src = l & 48;
    float rn[4];
#pragma unroll
    for (int e = 0; e < 4; ++e) rn[e] = 1.0f / __shfl(acc[4][e], src);
    const int rowg = c*CC + rowb;
#pragma unroll
    for (int e = 0; e < 4; ++e) {
        float* orow = out + (((size_t)b*SS + rowg + e)*HH + h)*DD + l15;
#pragma unroll
        for (int tc = 0; tc < 4; ++tc) orow[16*tc] = acc[tc][e] * rn[e];
    }
}

// ---------------------------------------------------------------------------
extern "C" void kernel_launch(void* const* d_in, const int* in_sizes, int n_in,
                              void* d_out, int out_size, void* d_ws, size_t ws_size,
                              hipStream_t stream) {
    const float* qk = (const float*)d_in[0];
    const float* v  = (const float*)d_in[1];
    float* out = (float*)d_out;
    float* ws  = (float*)d_ws;

    float* rec_g = ws;                                        // 512*4160 fp32 = 8.52 MB
    short* stp_g = (short*)(ws + (size_t)NCHK * RECF);        // 512*4160 bf16 = 4.26 MB
    short* kbuf  = stp_g + (size_t)NCHK * RECF;               // 512*8192 bf16 = 8.39 MB
    short* vtbuf = kbuf + (size_t)NCHK * (CC*DD);             // 512*8192 bf16 = 8.39 MB

    k_chunksum_mfma<<<dim3(NCHK), dim3(512), 0, stream>>>(qk, v, rec_g, kbuf, vtbuf);
    k_scan         <<<dim3(NCHK), dim3(256), 0, stream>>>(rec_g, stp_g);
    k_out_mfma     <<<dim3(NCHK), dim3(512), 0, stream>>>(qk, stp_g, kbuf, vtbuf, out);
}

// Round 7
// 31.622 us; speedup vs baseline: 4.2946x; 1.0176x over previous
//
#include <hip/hip_runtime.h>
#include <hip/hip_cooperative_groups.h>

namespace cg = cooperative_groups;

// Problem constants (B,S,H,D fixed by the reference)
#define BB   2
#define SS   2048
#define HH   16
#define DD   64
#define CC   128               // chunk length
#define NCH  (SS/CC)           // 16 chunks per (b,h)
#define RECF (DD*DD + DD)      // 4160 elems per record: State^T rows 0..63 + ksum row 64
#define BHN  (BB*HH)           // 32
#define NCHK (BHN*NCH)         // 512 chunk-blocks = exactly 2 blocks/CU x 256 CUs

typedef __attribute__((ext_vector_type(8))) short short8;
typedef __attribute__((ext_vector_type(4))) float f32x4;

// XOR swizzle of the s-index (units of 8 shorts) by LDS row — kills the
// transposed-write bank conflicts while keeping b128 reads contiguous.
#define SW(r) ((((r) >> 3) & 7) << 3)

__device__ __forceinline__ float elu1(float x) {
    return x > 0.0f ? x + 1.0f : __expf(x);
}
__device__ __forceinline__ short f2bf(float f) {
    union { float f; unsigned u; } x; x.f = f;
    unsigned r = x.u + 0x7FFFu + ((x.u >> 16) & 1u);   // RNE
    return (short)(r >> 16);
}
__device__ __forceinline__ float bf2f(short s) {
    union { unsigned u; float f; } x; x.u = ((unsigned)(unsigned short)s) << 16;
    return x.f;
}

// ---------------------------------------------------------------------------
// Fused cooperative kernel. LDS layout (units: shorts), total 31952 shorts
// = 63904 B <= 65536 B (the coop-launch occupancy validator's per-block cap;
// 2 x 63904 = 127808 <= 160 KB/CU -> 2 blocks/CU co-resident).
//   R0 [0,9216):        phase1 KT[64][136] / phase3 Sbh[128][72]
//   R1 [9216,13896):    StT[65][72]   (row 64 = ksum prefix)
//   R2 [13896,22736):   VT[65][136]   (rows 0-63 = V^T swizzled, row 64 = ones)
//   R3 [22736,31952):   Kb[128][72]   (K row-major bf16)
// tc=4 / rt=4 tile reads CLAMP their row index to 64 (broadcast of the
// ones/ksum row) so no reads ever touch undeclared rows; C-columns 65..79
// become copies of col 64 and are discarded.
// ---------------------------------------------------------------------------
#define OFF_STT 9216
#define OFF_VT  13896
#define OFF_KB  22736
#define NSMEM   31952

__device__ __forceinline__ void gridsync() {
    __threadfence();
    cg::this_grid().sync();
    __threadfence();
}

__global__ __launch_bounds__(512, 4) void k_fused(const float* __restrict__ qk,
                                                  const float* __restrict__ v,
                                                  short* __restrict__ rec_g,
                                                  short* __restrict__ stp_g,
                                                  float* __restrict__ out) {
    const int blk = blockIdx.x;
    const int c   = blk % NCH;
    const int bh  = blk / NCH;
    const int b = bh / HH, h = bh % HH;
    const int tid = threadIdx.x;
    const int w   = tid >> 6;
    const int l   = tid & 63;
    const int l15 = l & 15;
    const int g   = l >> 4;

    __shared__ __align__(16) short smem[NSMEM];
    short (*KT) [136] = (short(*)[136])(smem);
    short (*Sbh)[72]  = (short(*)[72]) (smem);
    short (*StT)[72]  = (short(*)[72]) (smem + OFF_STT);
    short (*VT) [136] = (short(*)[136])(smem + OFF_VT);
    short (*Kb) [72]  = (short(*)[72]) (smem + OFF_KB);

    // ================= Phase 1: stage K/V, compute per-chunk State^T ========
#pragma unroll
    for (int it = 0; it < 4; ++it) {
        const int f    = tid + it*512;      // float4 index 0..2047
        const int row  = f >> 4;            // s in chunk, 0..127
        const int col4 = (f & 15) * 4;      // d
        const int s = c*CC + row;
        float4 kq = *(const float4*)(qk + ((((size_t)b*SS + s)*2 + 1)*HH + h)*DD + col4);
        short4 kb;
        kb.x = f2bf(elu1(kq.x)); kb.y = f2bf(elu1(kq.y));
        kb.z = f2bf(elu1(kq.z)); kb.w = f2bf(elu1(kq.w));
        *(short4*)(&Kb[row][col4]) = kb;
        KT[col4+0][row ^ SW(col4+0)] = kb.x;
        KT[col4+1][row ^ SW(col4+1)] = kb.y;
        KT[col4+2][row ^ SW(col4+2)] = kb.z;
        KT[col4+3][row ^ SW(col4+3)] = kb.w;
        float4 vv = *(const float4*)(v + (((size_t)b*SS + s)*HH + h)*DD + col4);
        VT[col4+0][row ^ SW(col4+0)] = f2bf(vv.x);
        VT[col4+1][row ^ SW(col4+1)] = f2bf(vv.y);
        VT[col4+2][row ^ SW(col4+2)] = f2bf(vv.z);
        VT[col4+3][row ^ SW(col4+3)] = f2bf(vv.w);
    }
    if (tid < 128) VT[64][tid] = (short)0x3F80;   // ones row (SW(64)==0)
    __syncthreads();

    // State^T[t][d] (+ksum row 64) = [V^T; ones] . K. 8 waves: d-tile = w&3,
    // row-tile half = w>>2 (half 0: rt 0..2, half 1: rt 3..4).
    {
        const int dtile = w & 3;
        const int half  = w >> 2;
        const int nrt   = half ? 2 : 3;
        const int rt0   = half ? 3 : 0;
        f32x4 acc[3];
#pragma unroll
        for (int i = 0; i < 3; ++i) acc[i] = (f32x4){0.f,0.f,0.f,0.f};
        const int krow = 16*dtile + l15;
#pragma unroll
        for (int ks = 0; ks < 4; ++ks) {
            const int cb = 32*ks + 8*g;
            short8 bk = *(const short8*)(&KT[krow][cb ^ SW(krow)]);
#pragma unroll
            for (int i = 0; i < 3; ++i) {
                if (i < nrt) {
                    int arow = 16*(rt0 + i) + l15;
                    if (arow > 64) arow = 64;          // clamp into ones row
                    short8 a = *(const short8*)(&VT[arow][cb ^ SW(arow)]);
                    acc[i] = __builtin_amdgcn_mfma_f32_16x16x32_bf16(a, bk, acc[i], 0, 0, 0);
                }
            }
        }
        short* rec = rec_g + (size_t)blk * RECF;
#pragma unroll
        for (int i = 0; i < 3; ++i) {
            if (i < nrt) {
                const int rt = rt0 + i;
                if (rt < 4) {
#pragma unroll
                    for (int e = 0; e < 4; ++e)
                        rec[(16*rt + 4*g + e)*DD + 16*dtile + l15] = f2bf(acc[i][e]);
                } else if (g == 0) {
                    rec[4096 + 16*dtile + l15] = f2bf(acc[i][0]);   // ksum row
                }
            }
        }
    }

    gridsync();

    // ================= Phase 2: exclusive prefix scan over chunks ===========
    {
        const int sbh   = blk >> 4;
        const int slice = blk & 15;
        if (tid < 260) {
            const int elem = slice*260 + tid;
            float vals[16];
#pragma unroll
            for (int cc2 = 0; cc2 < 16; ++cc2)
                vals[cc2] = bf2f(rec_g[(size_t)(sbh*NCH + cc2)*RECF + elem]);
            float pref = 0.0f;
#pragma unroll
            for (int cc2 = 0; cc2 < 16; ++cc2) {
                stp_g[(size_t)(sbh*NCH + cc2)*RECF + elem] = f2bf(pref);
                pref += vals[cc2];
            }
        }
    }

    gridsync();

    // ================= Phase 3: O = [S | Q] . [V;ones ; State^T;ksum] =======
    const short* stp = stp_g + (size_t)blk * RECF;
    short8 st0 = *(const short8*)(stp + tid*8);
    short8 st1 = {};
    if (tid < 8) st1 = *(const short8*)(stp + 4096 + tid*8);

    // Q fragments (elu1 -> bf16), reused by QK^T and Q.State
    const int qrow = 16*w + l15;
    const float* qp = qk + ((((size_t)b*SS + (c*CC + qrow))*2 + 0)*HH + h)*DD;
    short8 aq[2];
#pragma unroll
    for (int ks = 0; ks < 2; ++ks) {
        const int k0 = 32*ks + 8*g;
        float4 t0 = *(const float4*)(qp + k0);
        float4 t1 = *(const float4*)(qp + k0 + 4);
        short8 a;
        a[0] = f2bf(elu1(t0.x)); a[1] = f2bf(elu1(t0.y));
        a[2] = f2bf(elu1(t0.z)); a[3] = f2bf(elu1(t0.w));
        a[4] = f2bf(elu1(t1.x)); a[5] = f2bf(elu1(t1.y));
        a[6] = f2bf(elu1(t1.z)); a[7] = f2bf(elu1(t1.w));
        aq[ks] = a;
    }

    // StT into R1 (untouched by phases 1-2)
    *(short8*)(&StT[tid >> 3][(tid & 7) * 8]) = st0;
    if (tid < 8) *(short8*)(&StT[64][tid * 8]) = st1;

    const int rowb = 16*w + 4*g;
    f32x4 acc[5];
#pragma unroll
    for (int t = 0; t < 5; ++t) acc[t] = (f32x4){0.f,0.f,0.f,0.f};

    // ---- S half A: cols s in [0,64) -> Sbh (overwrites dead KT) ----
#pragma unroll
    for (int tc = 0; tc < 4; ++tc) {
        f32x4 sacc = {0.f,0.f,0.f,0.f};
#pragma unroll
        for (int ks = 0; ks < 2; ++ks) {
            short8 bk = *(const short8*)(&Kb[16*tc + l15][32*ks + 8*g]);
            sacc = __builtin_amdgcn_mfma_f32_16x16x32_bf16(aq[ks], bk, sacc, 0, 0, 0);
        }
        const int colg = 16*tc + l15;
#pragma unroll
        for (int e = 0; e < 4; ++e) {
            const float sv = (colg <= rowb + e) ? sacc[e] : 0.0f;
            Sbh[rowb + e][colg] = f2bf(sv);
        }
    }
    __syncthreads();

    // ---- O += S_A.V (kj 0,1) + Q.State^T; tile 4 = denominator ----
#pragma unroll
    for (int kj = 0; kj < 2; ++kj) {
        short8 as = *(const short8*)(&Sbh[16*w + l15][32*kj + 8*g]);
#pragma unroll
        for (int tc = 0; tc < 5; ++tc) {
            int vrow = 16*tc + l15;
            if (vrow > 64) vrow = 64;                  // clamp into ones row
            short8 bv = *(const short8*)(&VT[vrow][(32*kj + 8*g) ^ SW(vrow)]);
            acc[tc] = __builtin_amdgcn_mfma_f32_16x16x32_bf16(as, bv, acc[tc], 0, 0, 0);
        }
    }
#pragma unroll
    for (int kd = 0; kd < 2; ++kd) {
#pragma unroll
        for (int tc = 0; tc < 5; ++tc) {
            int srow = 16*tc + l15;
            if (srow > 64) srow = 64;                  // clamp into ksum row
            short8 bs = *(const short8*)(&StT[srow][32*kd + 8*g]);
            acc[tc] = __builtin_amdgcn_mfma_f32_16x16x32_bf16(aq[kd], bs, acc[tc], 0, 0, 0);
        }
    }
    __syncthreads();

    // ---- S half B: cols s in [64,128) -> Sbh (local col = colg-64) ----
#pragma unroll
    for (int tc = 4; tc < 8; ++tc) {
        f32x4 sacc = {0.f,0.f,0.f,0.f};
#pragma unroll
        for (int ks = 0; ks < 2; ++ks) {
            short8 bk = *(const short8*)(&Kb[16*tc + l15][32*ks + 8*g]);
            sacc = __builtin_amdgcn_mfma_f32_16x16x32_bf16(aq[ks], bk, sacc, 0, 0, 0);
        }
        const int colg = 16*tc + l15;
#pragma unroll
        for (int e = 0; e < 4; ++e) {
            const float sv = (colg <= rowb + e) ? sacc[e] : 0.0f;
            Sbh[rowb + e][colg - 64] = f2bf(sv);
        }
    }
    __syncthreads();

    // ---- O += S_B.V (kj 2,3; global s = 64 + local) ----
#pragma unroll
    for (int kj = 2; kj < 4; ++kj) {
        short8 as = *(const short8*)(&Sbh[16*w + l15][32*(kj-2) + 8*g]);
#pragma unroll
        for (int tc = 0; tc < 5; ++tc) {
            int vrow = 16*tc + l15;
            if (vrow > 64) vrow = 64;
            short8 bv = *(const short8*)(&VT[vrow][(32*kj + 8*g) ^ SW(vrow)]);
            acc[tc] = __builtin_amdgcn_mfma_f32_16x16x32_bf16(as, bv, acc[tc], 0, 0, 0);
        }
    }

    // ---- epilogue: acc[4][e] IS the denominator in every lane (clamped
    //      B-tiles broadcast the ones/ksum column) -> no shuffle needed.
    float rn[4];
#pragma unroll
    for (int e = 0; e < 4; ++e) rn[e] = 1.0f / acc[4][e];
    const int rowg = c*CC + rowb;
#pragma unroll
    for (int e = 0; e < 4; ++e) {
        float* orow = out + (((size_t)b*SS + rowg + e)*HH + h)*DD + l15;
#pragma unroll
        for (int tc = 0; tc < 4; ++tc) orow[16*tc] = acc[tc][e] * rn[e];
    }
}

// ===========================================================================
// Fallback path (R5 structure, rec stored bf16) — used only if the
// cooperative launch cannot be validated/launched.
// ===========================================================================
__global__ __launch_bounds__(512) void k_chunksum_fb(const float* __restrict__ qk,
                                                     const float* __restrict__ v,
                                                     short* __restrict__ rec_g,
                                                     short* __restrict__ kbuf,
                                                     short* __restrict__ vtbuf) {
    const int blk = blockIdx.x;
    const int c   = blk % NCH;
    const int bh  = blk / NCH;
    const int b = bh / HH, h = bh % HH;
    const int tid = threadIdx.x;
    const int w   = tid >> 6;
    const int l   = tid & 63;
    const int l15 = l & 15;
    const int g   = l >> 4;

    __shared__ short KT[64][136];
    __shared__ short VT[80][136];

    short* kb_g = kbuf  + (size_t)blk * (CC*DD);
    short* vt_g = vtbuf + (size_t)blk * (DD*CC);

#pragma unroll
    for (int it = 0; it < 4; ++it) {
        const int f    = tid + it*512;
        const int row  = f >> 4;
        const int col4 = (f & 15) * 4;
        const int s = c*CC + row;
        float4 kq = *(const float4*)(qk + ((((size_t)b*SS + s)*2 + 1)*HH + h)*DD + col4);
        short4 kb;
        kb.x = f2bf(elu1(kq.x)); kb.y = f2bf(elu1(kq.y));
        kb.z = f2bf(elu1(kq.z)); kb.w = f2bf(elu1(kq.w));
        *(short4*)(kb_g + row*DD + col4) = kb;
        KT[col4+0][row ^ SW(col4+0)] = kb.x;
        KT[col4+1][row ^ SW(col4+1)] = kb.y;
        KT[col4+2][row ^ SW(col4+2)] = kb.z;
        KT[col4+3][row ^ SW(col4+3)] = kb.w;
        float4 vv = *(const float4*)(v + (((size_t)b*SS + s)*HH + h)*DD + col4);
        VT[col4+0][row ^ SW(col4+0)] = f2bf(vv.x);
        VT[col4+1][row ^ SW(col4+1)] = f2bf(vv.y);
        VT[col4+2][row ^ SW(col4+2)] = f2bf(vv.z);
        VT[col4+3][row ^ SW(col4+3)] = f2bf(vv.w);
    }
    if (tid < 128) VT[64][tid] = (short)0x3F80;
    __syncthreads();

#pragma unroll
    for (int it = 0; it < 2; ++it) {
        const int u  = tid + it*512;
        const int t  = u >> 4, s8 = (u & 15) * 8;
        short8 val = *(const short8*)(&VT[t][s8 ^ SW(t)]);
        *(short8*)(vt_g + t*CC + s8) = val;
    }

    const int dtile = w & 3;
    const int half  = w >> 2;
    const int nrt   = half ? 2 : 3;
    const int rt0   = half ? 3 : 0;
    f32x4 acc[3];
#pragma unroll
    for (int i = 0; i < 3; ++i) acc[i] = (f32x4){0.f,0.f,0.f,0.f};
    const int krow = 16*dtile + l15;
#pragma unroll
    for (int ks = 0; ks < 4; ++ks) {
        const int cb = 32*ks + 8*g;
        short8 bk = *(const short8*)(&KT[krow][cb ^ SW(krow)]);
#pragma unroll
        for (int i = 0; i < 3; ++i) {
            if (i < nrt) {
                const int arow = 16*(rt0 + i) + l15;
                short8 a = *(const short8*)(&VT[arow][cb ^ SW(arow)]);
                acc[i] = __builtin_amdgcn_mfma_f32_16x16x32_bf16(a, bk, acc[i], 0, 0, 0);
            }
        }
    }

    short* rec = rec_g + (size_t)blk * RECF;
#pragma unroll
    for (int i = 0; i < 3; ++i) {
        if (i < nrt) {
            const int rt = rt0 + i;
            if (rt < 4) {
#pragma unroll
                for (int e = 0; e < 4; ++e)
                    rec[(16*rt + 4*g + e)*DD + 16*dtile + l15] = f2bf(acc[i][e]);
            } else if (g == 0) {
                rec[4096 + 16*dtile + l15] = f2bf(acc[i][0]);
            }
        }
    }
}

__global__ __launch_bounds__(256) void k_scan_fb(const short* __restrict__ rec_g,
                                                 short* __restrict__ stp_g) {
    const int bh    = blockIdx.x >> 4;
    const int slice = blockIdx.x & 15;
#pragma unroll 1
    for (int ee = threadIdx.x; ee < 260; ee += 256) {
        const int elem = slice*260 + ee;
        float vals[16];
#pragma unroll
        for (int c = 0; c < 16; ++c)
            vals[c] = bf2f(rec_g[(size_t)(bh*NCH + c)*RECF + elem]);
        float pref = 0.0f;
#pragma unroll
        for (int c = 0; c < 16; ++c) {
            stp_g[(size_t)(bh*NCH + c)*RECF + elem] = f2bf(pref);
            pref += vals[c];
        }
    }
}

__global__ __launch_bounds__(512) void k_out_fb(const float* __restrict__ qk,
                                                const short* __restrict__ stp_g,
                                                const short* __restrict__ kbuf,
                                                const short* __restrict__ vtbuf,
                                                float* __restrict__ out) {
    const int blk = blockIdx.x;
    const int c   = blk % NCH;
    const int bh  = blk / NCH;
    const int b = bh / HH, h = bh % HH;
    const int tid = threadIdx.x;
    const int w   = tid >> 6;
    const int l   = tid & 63;
    const int l15 = l & 15;
    const int g   = l >> 4;

    __shared__ __align__(16) char smem[75008];
    short (*Kb)[72]   = (short(*)[72])smem;
    short (*StT)[72]  = (short(*)[72])smem;
    short (*Sb)[136]  = (short(*)[136])(smem + 18432);
    short (*VbT)[136] = (short(*)[136])(smem + 18432 + 34816);

    const short* kb_g = kbuf  + (size_t)blk * (CC*DD);
    const short* vt_g = vtbuf + (size_t)blk * (DD*CC);
    const short* stp  = stp_g + (size_t)blk * RECF;

#pragma unroll
    for (int it = 0; it < 2; ++it) {
        const int u = tid + it*512;
        const int row = u >> 3, col8 = (u & 7) * 8;
        *(short8*)(&Kb[row][col8]) = *(const short8*)(kb_g + row*DD + col8);
    }
#pragma unroll
    for (int it = 0; it < 2; ++it) {
        const int u = tid + it*512;
        const int t = u >> 4, s8 = (u & 15) * 8;
        *(short8*)(&VbT[t][s8]) = *(const short8*)(vt_g + t*CC + s8);
    }
    if (tid < 128) VbT[64][tid] = (short)0x3F80;

    short8 st0 = *(const short8*)(stp + tid*8);
    short8 st1 = {};
    if (tid < 8) st1 = *(const short8*)(stp + 4096 + tid*8);

    const int qrow = 16*w + l15;
    const float* qp = qk + ((((size_t)b*SS + (c*CC + qrow))*2 + 0)*HH + h)*DD;
    short8 aq[2];
#pragma unroll
    for (int ks = 0; ks < 2; ++ks) {
        const int k0 = 32*ks + 8*g;
        float4 t0 = *(const float4*)(qp + k0);
        float4 t1 = *(const float4*)(qp + k0 + 4);
        short8 a;
        a[0] = f2bf(elu1(t0.x)); a[1] = f2bf(elu1(t0.y));
        a[2] = f2bf(elu1(t0.z)); a[3] = f2bf(elu1(t0.w));
        a[4] = f2bf(elu1(t1.x)); a[5] = f2bf(elu1(t1.y));
        a[6] = f2bf(elu1(t1.z)); a[7] = f2bf(elu1(t1.w));
        aq[ks] = a;
    }
    __syncthreads();

    const int rowb = 16*w + 4*g;
#pragma unroll
    for (int tc = 0; tc < 8; ++tc) {
        f32x4 sacc = {0.f,0.f,0.f,0.f};
#pragma unroll
        for (int ks = 0; ks < 2; ++ks) {
            short8 bk = *(const short8*)(&Kb[16*tc + l15][32*ks + 8*g]);
            sacc = __builtin_amdgcn_mfma_f32_16x16x32_bf16(aq[ks], bk, sacc, 0, 0, 0);
        }
        const int colg = 16*tc + l15;
#pragma unroll
        for (int e = 0; e < 4; ++e) {
            const float sv = (colg <= rowb + e) ? sacc[e] : 0.0f;
            Sb[rowb + e][colg] = f2bf(sv);
        }
    }
    __syncthreads();

    *(short8*)(&StT[tid >> 3][(tid & 7) * 8]) = st0;
    if (tid < 8) *(short8*)(&StT[64][tid * 8]) = st1;

    f32x4 acc[5];
#pragma unroll
    for (int t = 0; t < 5; ++t) acc[t] = (f32x4){0.f,0.f,0.f,0.f};
#pragma unroll
    for (int kj = 0; kj < 4; ++kj) {
        short8 as = *(const short8*)(&Sb[16*w + l15][32*kj + 8*g]);
#pragma unroll
        for (int tc = 0; tc < 5; ++tc) {
            short8 bv = *(const short8*)(&VbT[16*tc + l15][32*kj + 8*g]);
            acc[tc] = __builtin_amdgcn_mfma_f32_16x16x32_bf16(as, bv, acc[tc], 0, 0, 0);
        }
    }
    __syncthreads();

#pragma unroll
    for (int kd = 0; kd < 2; ++kd) {
#pragma unroll
        for (int tc = 0; tc < 5; ++tc) {
            short8 bs = *(const short8*)(&StT[16*tc + l15][32*kd + 8*g]);
            acc[tc] = __builtin_amdgcn_mfma_f32_16x16x32_bf16(aq[kd], bs, acc[tc], 0, 0, 0);
        }
    }

    const int src = l & 48;
    float rn[4];
#pragma unroll
    for (int e = 0; e < 4; ++e) rn[e] = 1.0f / __shfl(acc[4][e], src);
    const int rowg = c*CC + rowb;
#pragma unroll
    for (int e = 0; e < 4; ++e) {
        float* orow = out + (((size_t)b*SS + rowg + e)*HH + h)*DD + l15;
#pragma unroll
        for (int tc = 0; tc < 4; ++tc) orow[16*tc] = acc[tc][e] * rn[e];
    }
}

// ---------------------------------------------------------------------------
extern "C" void kernel_launch(void* const* d_in, const int* in_sizes, int n_in,
                              void* d_out, int out_size, void* d_ws, size_t ws_size,
                              hipStream_t stream) {
    const float* qk = (const float*)d_in[0];
    const float* v  = (const float*)d_in[1];
    float* out = (float*)d_out;

    short* rec_g = (short*)d_ws;                       // 512*4160 bf16 = 4.26 MB
    short* stp_g = rec_g + (size_t)NCHK * RECF;        // 512*4160 bf16 = 4.26 MB
    short* kbuf  = stp_g + (size_t)NCHK * RECF;        // fallback only
    short* vtbuf = kbuf + (size_t)NCHK * (CC*DD);      // fallback only

    int occ = 0;
    hipError_t oe = hipOccupancyMaxActiveBlocksPerMultiprocessor(&occ, k_fused, 512, 0);
    bool launched = false;
    if (oe != hipSuccess || occ >= 2) {
        void* args[] = { (void*)&qk, (void*)&v, (void*)&rec_g, (void*)&stp_g, (void*)&out };
        hipError_t le = hipLaunchCooperativeKernel((const void*)k_fused, dim3(NCHK),
                                                   dim3(512), args, 0, stream);
        launched = (le == hipSuccess);
    }
    if (!launched) {
        k_chunksum_fb<<<dim3(NCHK), dim3(512), 0, stream>>>(qk, v, rec_g, kbuf, vtbuf);
        k_scan_fb    <<<dim3(NCHK), dim3(256), 0, stream>>>(rec_g, stp_g);
        k_out_fb     <<<dim3(NCHK), dim3(512), 0, stream>>>(qk, stp_g, kbuf, vtbuf, out);
    }
}